// Round 6
// baseline (501.705 us; speedup 1.0000x reference)
//
#include <hip/hip_runtime.h>
#include <hip/hip_bf16.h>

#define NN 100000   // nodes
#define NE 1600000  // edges
#define FD 128      // IN_DIM = H*D
#define CD 112      // CONTENT_DIM
#define PDIM 16     // POS_DIM
#define NH 4        // heads
#define NPB 32      // nodes per block (node_kernel)
#define SF 132      // LDS feat row stride (pad 128 -> 132, conflict-free)
#define NB_SCAN 391 // ceil(NN/256)
#define NSHARD 8    // dst shards (one per XCD)
#define SHARD 12500 // NN / NSHARD

// ---------------- K0: fold attention vectors into per-head 128-dim dots ----
// wA[h,k] (k<112)  = c0 * sum_d Wc[h*32+d, k] * attn_src[h*32+d]
// wA[h,112+k2]     = c1 * sum_d4 Wp[h*8+d4, k2] * pos_attn_src[h*8+d4]
// wB likewise with attn_dst / pos_attn_dst. Then A[n,h] = feat[n,:].wA[h,:].
__global__ __launch_bounds__(256) void prep_kernel(
    const float* __restrict__ Wc, const float* __restrict__ Wp,
    const float* __restrict__ attn_src, const float* __restrict__ attn_dst,
    const float* __restrict__ pos_attn_src, const float* __restrict__ pos_attn_dst,
    const float* __restrict__ att_comb,
    float* __restrict__ wA, float* __restrict__ wB)
{
    const int t = threadIdx.x;
    #pragma unroll
    for (int r = 0; r < 2; ++r) {
        const int idx = t + r * 256;       // 0..511
        const int h = idx >> 7, k = idx & 127;
        const float c0 = att_comb[h * 2], c1 = att_comb[h * 2 + 1];
        float sa = 0.f, sb = 0.f;
        if (k < CD) {
            #pragma unroll 8
            for (int d = 0; d < 32; ++d) {
                const float wv = Wc[(size_t)(h * 32 + d) * CD + k];
                sa = fmaf(wv, attn_src[h * 32 + d], sa);
                sb = fmaf(wv, attn_dst[h * 32 + d], sb);
            }
            sa *= c0; sb *= c0;
        } else {
            const int k2 = k - CD;
            #pragma unroll
            for (int d4 = 0; d4 < 8; ++d4) {
                const float wv = Wp[(h * 8 + d4) * PDIM + k2];
                sa = fmaf(wv, pos_attn_src[h * 8 + d4], sa);
                sb = fmaf(wv, pos_attn_dst[h * 8 + d4], sb);
            }
            sa *= c1; sb *= c1;
        }
        wA[h * FD + k] = sa;
        wB[h * FD + k] = sb;
    }
}

// ---------------- K1: degree histogram (XCD-sharded) ----------------
__global__ __launch_bounds__(256) void hist_kernel(const int* __restrict__ dst,
                                                   int* __restrict__ deg) {
    const int shard = blockIdx.x & (NSHARD - 1);
    const int i = (blockIdx.x >> 3) * 256 + threadIdx.x;  // grid exact
    const int d = dst[i];
    const int lo = shard * SHARD;
    if (d >= lo && d < lo + SHARD) atomicAdd(&deg[d], 1);
}

// ---------------- K2: node projections (pure dots, no shuffles) ----------
__global__ __launch_bounds__(256) void node_kernel(
    const float* __restrict__ feat, const float* __restrict__ Wc,
    const float* __restrict__ wA, const float* __restrict__ wB,
    __hip_bfloat16* __restrict__ hc_bf, float* __restrict__ A,
    float* __restrict__ B)
{
    const int t = threadIdx.x;
    const int n0 = blockIdx.x * NPB;
    __shared__ float fsh[NPB][SF];

    // stage feat for 32 nodes (coalesced reads, conflict-free LDS writes)
    #pragma unroll
    for (int r = 0; r < 16; ++r) {
        const int idx = t + r * 256;                 // 0..4095
        fsh[idx >> 7][idx & 127] = feat[(size_t)n0 * FD + idx];
    }
    __syncthreads();

    const int j = t & 127;     // output channel
    const int half = t >> 7;   // which 16-node subset
    float4 w[28];
    const float4* wrow = (const float4*)(Wc + j * CD);
    #pragma unroll
    for (int q = 0; q < 28; ++q) w[q] = wrow[q];

    for (int nn = 0; nn < 16; ++nn) {
        const int n = half * 16 + nn;
        float acc = 0.f;
        #pragma unroll
        for (int q = 0; q < 28; ++q) {
            const float4 fv = *(const float4*)&fsh[n][4 * q];  // broadcast
            acc = fmaf(w[q].x, fv.x, acc);
            acc = fmaf(w[q].y, fv.y, acc);
            acc = fmaf(w[q].z, fv.z, acc);
            acc = fmaf(w[q].w, fv.w, acc);
        }
        hc_bf[(size_t)(n0 + n) * FD + j] = __float2bfloat16(acc);
    }

    // A/B: 32 nodes x 8 (head, src/dst) 128-dim dots; fsh is read-only since
    // staging, so no extra barrier needed.
    const int nb = t >> 3, q = t & 7, h = q >> 1;
    const float4* wv = (const float4*)(((q & 1) ? wB : wA) + h * FD);
    float acc2 = 0.f;
    #pragma unroll
    for (int x = 0; x < 32; ++x) {
        const float4 fv = *(const float4*)&fsh[nb][4 * x];
        const float4 ww = wv[x];
        acc2 = fmaf(ww.x, fv.x, acc2);
        acc2 = fmaf(ww.y, fv.y, acc2);
        acc2 = fmaf(ww.z, fv.z, acc2);
        acc2 = fmaf(ww.w, fv.w, acc2);
    }
    if (q & 1) B[(size_t)(n0 + nb) * NH + h] = acc2;
    else       A[(size_t)(n0 + nb) * NH + h] = acc2;
}

// ---------------- K3: scan (3 stages) ----------------
__global__ __launch_bounds__(256) void scan1_kernel(const int* __restrict__ deg,
                                                    int* __restrict__ tmp,
                                                    int* __restrict__ bsum) {
    __shared__ int sh[256];
    const int t = threadIdx.x, b = blockIdx.x, i = b * 256 + t;
    const int v = (i < NN) ? deg[i] : 0;
    sh[t] = v;
    __syncthreads();
    #pragma unroll
    for (int off = 1; off < 256; off <<= 1) {
        const int x = (t >= off) ? sh[t - off] : 0;
        __syncthreads();
        sh[t] += x;
        __syncthreads();
    }
    if (i < NN) tmp[i] = sh[t] - v;   // exclusive
    if (t == 255) bsum[b] = sh[t];
}

__global__ __launch_bounds__(512) void scan2_kernel(int* __restrict__ bsum) {
    __shared__ int sh[512];
    const int t = threadIdx.x;
    const int v = (t < NB_SCAN) ? bsum[t] : 0;
    sh[t] = v;
    __syncthreads();
    #pragma unroll
    for (int off = 1; off < 512; off <<= 1) {
        const int x = (t >= off) ? sh[t - off] : 0;
        __syncthreads();
        sh[t] += x;
        __syncthreads();
    }
    if (t < NB_SCAN) bsum[t] = sh[t] - v;   // exclusive
}

__global__ __launch_bounds__(256) void scan3_kernel(const int* __restrict__ tmp,
                                                    const int* __restrict__ bsum,
                                                    int* __restrict__ row_ptr,
                                                    int* __restrict__ cursor) {
    const int i = blockIdx.x * 256 + threadIdx.x;
    if (i < NN) {
        const int v = tmp[i] + bsum[blockIdx.x];
        row_ptr[i] = v;
        cursor[i] = v;
    }
    if (i == 0) row_ptr[NN] = NE;
}

// ---------------- K4: scatter edges into CSR (XCD-sharded) ----------------
__global__ __launch_bounds__(256) void scatter_kernel(
    const int* __restrict__ src, const int* __restrict__ dst,
    int* __restrict__ cursor, int* __restrict__ col)
{
    const int shard = blockIdx.x & (NSHARD - 1);
    const int i = (blockIdx.x >> 3) * 256 + threadIdx.x;  // grid exact
    const int d = dst[i];
    const int s = src[i];
    const int lo = shard * SHARD;
    if (d >= lo && d < lo + SHARD) {
        const int p = atomicAdd(&cursor[d], 1);
        col[p] = s;
    }
}

// ---------------- K5: per-node fused softmax + aggregate ----------------
// One 64-lane wave per node; lane l owns channels 2l,2l+1 (head = l>>4).
// Unroll 8: lane hme*16+(l&7) computes the exp-chain for edge p+(l&7) only;
// weights broadcast to the head group via __shfl (ds_bpermute, LDS pipe).
__global__ __launch_bounds__(256) void agg_kernel(
    const int* __restrict__ row_ptr, const int* __restrict__ col,
    const float* __restrict__ A, const float* __restrict__ B,
    const unsigned int* __restrict__ hc_u,
    const float* __restrict__ feat, float* __restrict__ out)
{
    const int n = blockIdx.x * 4 + (threadIdx.x >> 6);
    const int l = threadIdx.x & 63;
    const int hme = l >> 4;
    const int base = l & 48;          // first lane of my head group
    const int r0 = row_ptr[n], r1 = row_ptr[n + 1];
    const float bh = B[(size_t)n * NH + hme];   // scalar, broadcast in group

    float ssum = 0.f, acc0 = 0.f, acc1 = 0.f;
    int p = r0;
    for (; p + 8 <= r1; p += 8) {
        int c[8];
        #pragma unroll
        for (int k = 0; k < 8; ++k) c[k] = col[p + k];
        unsigned int u[8];
        #pragma unroll
        for (int k = 0; k < 8; ++k) u[k] = hc_u[(size_t)c[k] * 64 + l];
        // this lane's own edge: compute w once, share via bpermute
        const int ck = col[p + (l & 7)];
        float e = A[(size_t)ck * NH + hme] + bh;
        e = e > 0.f ? e : 0.2f * e;
        const float w = __expf(e);
        float wk[8];
        #pragma unroll
        for (int k = 0; k < 8; ++k) wk[k] = __shfl(w, base | k);
        ssum += ((wk[0] + wk[1]) + (wk[2] + wk[3])) +
                ((wk[4] + wk[5]) + (wk[6] + wk[7]));
        #pragma unroll
        for (int k = 0; k < 8; ++k) {
            acc0 = fmaf(wk[k], __uint_as_float(u[k] << 16), acc0);
            acc1 = fmaf(wk[k], __uint_as_float(u[k] & 0xffff0000u), acc1);
        }
    }
    for (; p < r1; ++p) {
        const int c = col[p];
        const unsigned int u = hc_u[(size_t)c * 64 + l];
        float e = A[(size_t)c * NH + hme] + bh;
        e = e > 0.f ? e : 0.2f * e;
        const float w = __expf(e);
        ssum += w;
        acc0 = fmaf(w, __uint_as_float(u << 16), acc0);
        acc1 = fmaf(w, __uint_as_float(u & 0xffff0000u), acc1);
    }

    const float inv = ssum > 0.f ? 1.f / ssum : 0.f;
    const float2 fv = ((const float2*)(feat + (size_t)n * FD))[l];
    float2 ov;
    ov.x = acc0 * inv + fv.x;
    ov.y = acc1 * inv + fv.y;
    ((float2*)(out + (size_t)n * FD))[l] = ov;
    if (blockIdx.x == 0 && threadIdx.x == 0) out[(size_t)NN * FD] = 0.f;
}

// ---------------- launcher ----------------
extern "C" void kernel_launch(void* const* d_in, const int* in_sizes, int n_in,
                              void* d_out, int out_size, void* d_ws, size_t ws_size,
                              hipStream_t stream) {
    const float* feat         = (const float*)d_in[0];
    const int*   src          = (const int*)d_in[1];
    const int*   dst          = (const int*)d_in[2];
    const float* Wc           = (const float*)d_in[3];
    const float* Wp           = (const float*)d_in[4];
    const float* attn_src     = (const float*)d_in[5];
    const float* attn_dst     = (const float*)d_in[6];
    const float* pos_attn_src = (const float*)d_in[7];
    const float* pos_attn_dst = (const float*)d_in[8];
    const float* att_comb     = (const float*)d_in[9];
    float* out = (float*)d_out;

    // workspace layout (all 16B-aligned)
    char* w = (char*)d_ws;
    __hip_bfloat16* hc_bf = (__hip_bfloat16*)w;        w += (size_t)NN * FD * 2;  // 25.6 MB
    float* A       = (float*)w;                        w += (size_t)NN * NH * 4;  // 1.6 MB
    float* B       = (float*)w;                        w += (size_t)NN * NH * 4;  // 1.6 MB
    int*   deg     = (int*)w;                          w += (size_t)NN * 4;
    int*   tmp     = (int*)w;                          w += (size_t)NN * 4;
    int*   row_ptr = (int*)w;                          w += (size_t)(NN + 4) * 4;
    int*   cursor  = (int*)w;                          w += (size_t)NN * 4;
    int*   bsum    = (int*)w;                          w += 512 * 4;
    float* wA      = (float*)w;                        w += NH * FD * 4;
    float* wB      = (float*)w;                        w += NH * FD * 4;
    int*   col     = (int*)w;                          /* NE*4 = 6.4 MB */

    hipMemsetAsync(deg, 0, (size_t)NN * sizeof(int), stream);
    prep_kernel<<<1, 256, 0, stream>>>(Wc, Wp, attn_src, attn_dst,
                                       pos_attn_src, pos_attn_dst, att_comb,
                                       wA, wB);
    hist_kernel<<<NSHARD * (NE / 256), 256, 0, stream>>>(dst, deg);
    node_kernel<<<NN / NPB, 256, 0, stream>>>(feat, Wc, wA, wB, hc_bf, A, B);
    scan1_kernel<<<NB_SCAN, 256, 0, stream>>>(deg, tmp, bsum);
    scan2_kernel<<<1, 512, 0, stream>>>(bsum);
    scan3_kernel<<<NB_SCAN, 256, 0, stream>>>(tmp, bsum, row_ptr, cursor);
    scatter_kernel<<<NSHARD * (NE / 256), 256, 0, stream>>>(src, dst, cursor, col);
    agg_kernel<<<NN / 4, 256, 0, stream>>>(row_ptr, col, A, B,
                                           (const unsigned int*)hc_bf, feat, out);
}

// Round 7
// 394.900 us; speedup vs baseline: 1.2705x; 1.2705x over previous
//
#include <hip/hip_runtime.h>
#include <hip/hip_bf16.h>

#define NN 100000   // nodes
#define NE 1600000  // edges
#define FD 128      // IN_DIM = H*D
#define CD 112      // CONTENT_DIM
#define PDIM 16     // POS_DIM
#define NH 4        // heads
#define NB_SCAN 391 // ceil(NN/256)
#define NSHARD 8    // dst shards (one per XCD)
#define SHARD 12500 // NN / NSHARD

#define NOUT 144        // 128 hc cols + 4 A + 4 B + 8 pad
#define MBLK 64         // nodes per block in node GEMM
#define LDS_STRIDE 136  // ushort stride per LDS row (128 + 8 pad -> 2-way-only bank aliasing)
#define WT_U (MBLK * LDS_STRIDE)  // 8704: ushort offset of WT region
#define NGB 1563        // ceil(NN / MBLK)

using bf16x8 = __attribute__((ext_vector_type(8))) short;
using f32x4  = __attribute__((ext_vector_type(4))) float;

__device__ __forceinline__ unsigned short f2bf(float x) {
    union { float f; unsigned int u; } v; v.f = x;
    return (unsigned short)((v.u + 0x7fffu + ((v.u >> 16) & 1u)) >> 16);  // RNE
}

// ---------------- K0: build combined bf16 weight matrix W'T [144][128] ----
// rows 0..127: Wc[j, 0:112] (cols 112..127 zero)  -> hc = feat . W'T[j]
// rows 128+h : wA[h] = fold(attn_src)  -> A logits
// rows 132+h : wB[h] = fold(attn_dst)  -> B logits
// rows 136..143: zero padding
__global__ __launch_bounds__(256) void prep_kernel(
    const float* __restrict__ Wc, const float* __restrict__ Wp,
    const float* __restrict__ attn_src, const float* __restrict__ attn_dst,
    const float* __restrict__ pos_attn_src, const float* __restrict__ pos_attn_dst,
    const float* __restrict__ att_comb, unsigned short* __restrict__ wt)
{
    __shared__ float sA[NH * FD], sB[NH * FD];
    const int t = threadIdx.x;
    #pragma unroll
    for (int r = 0; r < 2; ++r) {
        const int idx = t + r * 256;       // 0..511
        const int h = idx >> 7, k = idx & 127;
        const float c0 = att_comb[h * 2], c1 = att_comb[h * 2 + 1];
        float sa = 0.f, sb = 0.f;
        if (k < CD) {
            #pragma unroll 8
            for (int d = 0; d < 32; ++d) {
                const float wv = Wc[(size_t)(h * 32 + d) * CD + k];
                sa = fmaf(wv, attn_src[h * 32 + d], sa);
                sb = fmaf(wv, attn_dst[h * 32 + d], sb);
            }
            sa *= c0; sb *= c0;
        } else {
            const int k2 = k - CD;
            #pragma unroll
            for (int d4 = 0; d4 < 8; ++d4) {
                const float wv = Wp[(h * 8 + d4) * PDIM + k2];
                sa = fmaf(wv, pos_attn_src[h * 8 + d4], sa);
                sb = fmaf(wv, pos_attn_dst[h * 8 + d4], sb);
            }
            sa *= c1; sb *= c1;
        }
        sA[idx] = sa; sB[idx] = sb;
    }
    __syncthreads();
    #pragma unroll
    for (int it = 0; it < 72; ++it) {
        const int e = t + it * 256;        // < 18432 = 144*128
        const int row = e >> 7, k = e & 127;
        float val;
        if (row < 128)      val = (k < CD) ? Wc[(size_t)row * CD + k] : 0.f;
        else if (row < 132) val = sA[(row - 128) * FD + k];
        else if (row < 136) val = sB[(row - 132) * FD + k];
        else                val = 0.f;
        wt[e] = f2bf(val);
    }
}

// ---------------- K1: degree histogram (XCD-sharded) ----------------
__global__ __launch_bounds__(256) void hist_kernel(const int* __restrict__ dst,
                                                   int* __restrict__ deg) {
    const int shard = blockIdx.x & (NSHARD - 1);
    const int i = (blockIdx.x >> 3) * 256 + threadIdx.x;  // grid exact
    const int d = dst[i];
    const int lo = shard * SHARD;
    if (d >= lo && d < lo + SHARD) atomicAdd(&deg[d], 1);
}

// ---------------- K2: node projections via MFMA ----------------
// [64 nodes x 128] x [128 x 144] per block; 4 waves, each one 16-row M-tile.
// Fragment maps (m89/m120-verified): A[m=lane&15][k=quad*8+j],
// B[k=quad*8+j][n=lane&15], C/D col=lane&15, row=quad*4+reg.
__global__ __launch_bounds__(256) void node_mfma_kernel(
    const float* __restrict__ feat, const unsigned short* __restrict__ wt,
    unsigned short* __restrict__ hc_bf, float* __restrict__ A,
    float* __restrict__ B)
{
    __shared__ unsigned short sm[WT_U + NOUT * LDS_STRIDE];  // 56,576 B
    unsigned int* smu = (unsigned int*)sm;
    const int t = threadIdx.x;
    const int n0 = blockIdx.x * MBLK;

    // stage feat rows (f32 -> packed bf16 pairs), guarded for the tail block
    #pragma unroll
    for (int it = 0; it < 16; ++it) {
        const int e2 = t + it * 256;           // pair index < 4096 (64x64)
        const int row = e2 >> 6, c2 = e2 & 63;
        unsigned int packed = 0;
        if (n0 + row < NN) {
            const float2 g = ((const float2*)(feat + (size_t)n0 * FD))[e2];
            packed = (unsigned int)f2bf(g.x) | ((unsigned int)f2bf(g.y) << 16);
        }
        smu[row * (LDS_STRIDE / 2) + c2] = packed;
    }
    // stage W'T (already bf16 in global, compact 144x128)
    const unsigned int* wtu = (const unsigned int*)wt;
    #pragma unroll
    for (int it = 0; it < 36; ++it) {
        const int u = t + it * 256;            // < 9216
        const int row = u >> 6, c2 = u & 63;
        smu[WT_U / 2 + row * (LDS_STRIDE / 2) + c2] = wtu[u];
    }
    __syncthreads();

    const int w = t >> 6;          // wave id = M-tile
    const int lane = t & 63;
    const int mr = lane & 15, quad = lane >> 4;

    f32x4 acc[9];
    #pragma unroll
    for (int i = 0; i < 9; ++i) acc[i] = (f32x4){0.f, 0.f, 0.f, 0.f};

    #pragma unroll
    for (int kk = 0; kk < 4; ++kk) {
        const bf16x8 a =
            *(const bf16x8*)&sm[(w * 16 + mr) * LDS_STRIDE + kk * 32 + quad * 8];
        #pragma unroll
        for (int tt = 0; tt < 9; ++tt) {
            const bf16x8 b = *(const bf16x8*)&sm[WT_U + (tt * 16 + mr) * LDS_STRIDE +
                                                 kk * 32 + quad * 8];
            acc[tt] = __builtin_amdgcn_mfma_f32_16x16x32_bf16(a, b, acc[tt], 0, 0, 0);
        }
    }

    // epilogue: tiles 0..7 -> hc (bf16); tile 8 cols 0..3 -> A, 4..7 -> B
    #pragma unroll
    for (int tt = 0; tt < 8; ++tt) {
        const int col = tt * 16 + mr;
        #pragma unroll
        for (int r = 0; r < 4; ++r) {
            const int node = n0 + w * 16 + quad * 4 + r;
            if (node < NN) hc_bf[(size_t)node * FD + col] = f2bf(acc[tt][r]);
        }
    }
    #pragma unroll
    for (int r = 0; r < 4; ++r) {
        const int node = n0 + w * 16 + quad * 4 + r;
        if (node < NN) {
            if (mr < 4)      A[(size_t)node * NH + mr] = acc[8][r];
            else if (mr < 8) B[(size_t)node * NH + (mr - 4)] = acc[8][r];
        }
    }
}

// ---------------- K3: scan (3 stages) ----------------
__global__ __launch_bounds__(256) void scan1_kernel(const int* __restrict__ deg,
                                                    int* __restrict__ tmp,
                                                    int* __restrict__ bsum) {
    __shared__ int sh[256];
    const int t = threadIdx.x, b = blockIdx.x, i = b * 256 + t;
    const int v = (i < NN) ? deg[i] : 0;
    sh[t] = v;
    __syncthreads();
    #pragma unroll
    for (int off = 1; off < 256; off <<= 1) {
        const int x = (t >= off) ? sh[t - off] : 0;
        __syncthreads();
        sh[t] += x;
        __syncthreads();
    }
    if (i < NN) tmp[i] = sh[t] - v;   // exclusive
    if (t == 255) bsum[b] = sh[t];
}

__global__ __launch_bounds__(512) void scan2_kernel(int* __restrict__ bsum) {
    __shared__ int sh[512];
    const int t = threadIdx.x;
    const int v = (t < NB_SCAN) ? bsum[t] : 0;
    sh[t] = v;
    __syncthreads();
    #pragma unroll
    for (int off = 1; off < 512; off <<= 1) {
        const int x = (t >= off) ? sh[t - off] : 0;
        __syncthreads();
        sh[t] += x;
        __syncthreads();
    }
    if (t < NB_SCAN) bsum[t] = sh[t] - v;   // exclusive
}

__global__ __launch_bounds__(256) void scan3_kernel(const int* __restrict__ tmp,
                                                    const int* __restrict__ bsum,
                                                    int* __restrict__ row_ptr,
                                                    int* __restrict__ cursor) {
    const int i = blockIdx.x * 256 + threadIdx.x;
    if (i < NN) {
        const int v = tmp[i] + bsum[blockIdx.x];
        row_ptr[i] = v;
        cursor[i] = v;
    }
    if (i == 0) row_ptr[NN] = NE;
}

// ---------------- K4: scatter edges into CSR (XCD-sharded) ----------------
__global__ __launch_bounds__(256) void scatter_kernel(
    const int* __restrict__ src, const int* __restrict__ dst,
    int* __restrict__ cursor, int* __restrict__ col)
{
    const int shard = blockIdx.x & (NSHARD - 1);
    const int i = (blockIdx.x >> 3) * 256 + threadIdx.x;  // grid exact
    const int d = dst[i];
    const int s = src[i];
    const int lo = shard * SHARD;
    if (d >= lo && d < lo + SHARD) {
        const int p = atomicAdd(&cursor[d], 1);
        col[p] = s;
    }
}

// ---------------- K5: per-node fused softmax + aggregate ----------------
// One 64-lane wave per node; lane l owns channels 2l,2l+1 (head = l>>4).
// Unroll 8: lane hme*16+(l&7) computes the exp-chain for edge p+(l&7) only;
// weights broadcast to the head group via __shfl (ds_bpermute, LDS pipe).
__global__ __launch_bounds__(256) void agg_kernel(
    const int* __restrict__ row_ptr, const int* __restrict__ col,
    const float* __restrict__ A, const float* __restrict__ B,
    const unsigned int* __restrict__ hc_u,
    const float* __restrict__ feat, float* __restrict__ out)
{
    const int n = blockIdx.x * 4 + (threadIdx.x >> 6);
    const int l = threadIdx.x & 63;
    const int hme = l >> 4;
    const int base = l & 48;          // first lane of my head group
    const int r0 = row_ptr[n], r1 = row_ptr[n + 1];
    const float bh = B[(size_t)n * NH + hme];   // scalar, broadcast in group

    float ssum = 0.f, acc0 = 0.f, acc1 = 0.f;
    int p = r0;
    for (; p + 8 <= r1; p += 8) {
        int c[8];
        #pragma unroll
        for (int k = 0; k < 8; ++k) c[k] = col[p + k];
        unsigned int u[8];
        #pragma unroll
        for (int k = 0; k < 8; ++k) u[k] = hc_u[(size_t)c[k] * 64 + l];
        // this lane's own edge: compute w once, share via bpermute
        const int ck = col[p + (l & 7)];
        float e = A[(size_t)ck * NH + hme] + bh;
        e = e > 0.f ? e : 0.2f * e;
        const float w = __expf(e);
        float wk[8];
        #pragma unroll
        for (int k = 0; k < 8; ++k) wk[k] = __shfl(w, base | k);
        ssum += ((wk[0] + wk[1]) + (wk[2] + wk[3])) +
                ((wk[4] + wk[5]) + (wk[6] + wk[7]));
        #pragma unroll
        for (int k = 0; k < 8; ++k) {
            acc0 = fmaf(wk[k], __uint_as_float(u[k] << 16), acc0);
            acc1 = fmaf(wk[k], __uint_as_float(u[k] & 0xffff0000u), acc1);
        }
    }
    for (; p < r1; ++p) {
        const int c = col[p];
        const unsigned int u = hc_u[(size_t)c * 64 + l];
        float e = A[(size_t)c * NH + hme] + bh;
        e = e > 0.f ? e : 0.2f * e;
        const float w = __expf(e);
        ssum += w;
        acc0 = fmaf(w, __uint_as_float(u << 16), acc0);
        acc1 = fmaf(w, __uint_as_float(u & 0xffff0000u), acc1);
    }

    const float inv = ssum > 0.f ? 1.f / ssum : 0.f;
    const float2 fv = ((const float2*)(feat + (size_t)n * FD))[l];
    float2 ov;
    ov.x = acc0 * inv + fv.x;
    ov.y = acc1 * inv + fv.y;
    ((float2*)(out + (size_t)n * FD))[l] = ov;
    if (blockIdx.x == 0 && threadIdx.x == 0) out[(size_t)NN * FD] = 0.f;
}

// ---------------- launcher ----------------
extern "C" void kernel_launch(void* const* d_in, const int* in_sizes, int n_in,
                              void* d_out, int out_size, void* d_ws, size_t ws_size,
                              hipStream_t stream) {
    const float* feat         = (const float*)d_in[0];
    const int*   src          = (const int*)d_in[1];
    const int*   dst          = (const int*)d_in[2];
    const float* Wc           = (const float*)d_in[3];
    const float* Wp           = (const float*)d_in[4];
    const float* attn_src     = (const float*)d_in[5];
    const float* attn_dst     = (const float*)d_in[6];
    const float* pos_attn_src = (const float*)d_in[7];
    const float* pos_attn_dst = (const float*)d_in[8];
    const float* att_comb     = (const float*)d_in[9];
    float* out = (float*)d_out;

    // workspace layout (all 16B-aligned)
    char* w = (char*)d_ws;
    unsigned short* hc_bf = (unsigned short*)w;        w += (size_t)NN * FD * 2;  // 25.6 MB
    float* A       = (float*)w;                        w += (size_t)NN * NH * 4;  // 1.6 MB
    float* B       = (float*)w;                        w += (size_t)NN * NH * 4;  // 1.6 MB
    int*   deg     = (int*)w;                          w += (size_t)NN * 4;
    int*   tmp     = (int*)w;                          w += (size_t)NN * 4;
    int*   row_ptr = (int*)w;                          w += (size_t)(NN + 4) * 4;
    int*   cursor  = (int*)w;                          w += (size_t)NN * 4;
    int*   bsum    = (int*)w;                          w += 512 * 4;
    unsigned short* wt = (unsigned short*)w;           w += (size_t)NOUT * FD * 2; // 36.9 KB
    int*   col     = (int*)w;                          /* NE*4 = 6.4 MB */

    hipMemsetAsync(deg, 0, (size_t)NN * sizeof(int), stream);
    prep_kernel<<<1, 256, 0, stream>>>(Wc, Wp, attn_src, attn_dst,
                                       pos_attn_src, pos_attn_dst, att_comb, wt);
    hist_kernel<<<NSHARD * (NE / 256), 256, 0, stream>>>(dst, deg);
    node_mfma_kernel<<<NGB, 256, 0, stream>>>(feat, wt, hc_bf, A, B);
    scan1_kernel<<<NB_SCAN, 256, 0, stream>>>(deg, tmp, bsum);
    scan2_kernel<<<1, 512, 0, stream>>>(bsum);
    scan3_kernel<<<NB_SCAN, 256, 0, stream>>>(tmp, bsum, row_ptr, cursor);
    scatter_kernel<<<NSHARD * (NE / 256), 256, 0, stream>>>(src, dst, cursor, col);
    agg_kernel<<<NN / 4, 256, 0, stream>>>(row_ptr, col, A, B,
                                           (const unsigned int*)hc_bf, feat, out);
}

// Round 8
// 387.362 us; speedup vs baseline: 1.2952x; 1.0195x over previous
//
#include <hip/hip_runtime.h>
#include <hip/hip_bf16.h>

#define NN 100000   // nodes
#define NE 1600000  // edges
#define FD 128      // IN_DIM = H*D
#define CD 112      // CONTENT_DIM
#define PDIM 16     // POS_DIM
#define NH 4        // heads
#define NB_SCAN 391 // ceil(NN/256)
#define NSHARD 8    // dst shards (one per XCD)
#define SHARD 12500 // NN / NSHARD
#define NE4 400000  // NE / 4
#define NB_E4 1563  // ceil(NE4 / 256)

#define NOUT 144        // 128 hc cols + 4 A + 4 B + 8 pad
#define MBLK 64         // nodes per block in node GEMM
#define LDS_STRIDE 136  // ushort stride per LDS row
#define WT_U (MBLK * LDS_STRIDE)
#define NGB 1563        // ceil(NN / MBLK)

using bf16x8 = __attribute__((ext_vector_type(8))) short;
using f32x4  = __attribute__((ext_vector_type(4))) float;

__device__ __forceinline__ unsigned short f2bf(float x) {
    union { float f; unsigned int u; } v; v.f = x;
    return (unsigned short)((v.u + 0x7fffu + ((v.u >> 16) & 1u)) >> 16);  // RNE
}
__device__ __forceinline__ float bf_lo(unsigned int u) { return __uint_as_float(u << 16); }
__device__ __forceinline__ float bf_hi(unsigned int u) { return __uint_as_float(u & 0xffff0000u); }

// ---------------- K0: build combined bf16 weight matrix W'T [144][128] ----
__global__ __launch_bounds__(256) void prep_kernel(
    const float* __restrict__ Wc, const float* __restrict__ Wp,
    const float* __restrict__ attn_src, const float* __restrict__ attn_dst,
    const float* __restrict__ pos_attn_src, const float* __restrict__ pos_attn_dst,
    const float* __restrict__ att_comb, unsigned short* __restrict__ wt)
{
    __shared__ float sA[NH * FD], sB[NH * FD];
    const int t = threadIdx.x;
    #pragma unroll
    for (int r = 0; r < 2; ++r) {
        const int idx = t + r * 256;       // 0..511
        const int h = idx >> 7, k = idx & 127;
        const float c0 = att_comb[h * 2], c1 = att_comb[h * 2 + 1];
        float sa = 0.f, sb = 0.f;
        if (k < CD) {
            #pragma unroll 8
            for (int d = 0; d < 32; ++d) {
                const float wv = Wc[(size_t)(h * 32 + d) * CD + k];
                sa = fmaf(wv, attn_src[h * 32 + d], sa);
                sb = fmaf(wv, attn_dst[h * 32 + d], sb);
            }
            sa *= c0; sb *= c0;
        } else {
            const int k2 = k - CD;
            #pragma unroll
            for (int d4 = 0; d4 < 8; ++d4) {
                const float wv = Wp[(h * 8 + d4) * PDIM + k2];
                sa = fmaf(wv, pos_attn_src[h * 8 + d4], sa);
                sb = fmaf(wv, pos_attn_dst[h * 8 + d4], sb);
            }
            sa *= c1; sb *= c1;
        }
        sA[idx] = sa; sB[idx] = sb;
    }
    __syncthreads();
    #pragma unroll
    for (int it = 0; it < 72; ++it) {
        const int e = t + it * 256;        // < 18432 = 144*128
        const int row = e >> 7, k = e & 127;
        float val;
        if (row < 128)      val = (k < CD) ? Wc[(size_t)row * CD + k] : 0.f;
        else if (row < 132) val = sA[(row - 128) * FD + k];
        else if (row < 136) val = sB[(row - 132) * FD + k];
        else                val = 0.f;
        wt[e] = f2bf(val);
    }
}

// ---------------- K1: degree histogram (XCD-sharded, int4) ----------------
__global__ __launch_bounds__(256) void hist_kernel(const int* __restrict__ dst,
                                                   int* __restrict__ deg) {
    const int shard = blockIdx.x & (NSHARD - 1);
    const int i4 = (blockIdx.x >> 3) * 256 + threadIdx.x;
    if (i4 >= NE4) return;
    const int4 d4 = ((const int4*)dst)[i4];
    const int lo = shard * SHARD, hi = lo + SHARD;
    if (d4.x >= lo && d4.x < hi) atomicAdd(&deg[d4.x], 1);
    if (d4.y >= lo && d4.y < hi) atomicAdd(&deg[d4.y], 1);
    if (d4.z >= lo && d4.z < hi) atomicAdd(&deg[d4.z], 1);
    if (d4.w >= lo && d4.w < hi) atomicAdd(&deg[d4.w], 1);
}

// ---------------- K2: node projections via MFMA ----------------
__global__ __launch_bounds__(256) void node_mfma_kernel(
    const float* __restrict__ feat, const unsigned short* __restrict__ wt,
    unsigned short* __restrict__ hc_bf, float* __restrict__ A,
    float* __restrict__ B)
{
    __shared__ unsigned short sm[WT_U + NOUT * LDS_STRIDE];  // 56,576 B
    unsigned int* smu = (unsigned int*)sm;
    const int t = threadIdx.x;
    const int n0 = blockIdx.x * MBLK;

    #pragma unroll
    for (int it = 0; it < 16; ++it) {
        const int e2 = t + it * 256;           // pair index < 4096 (64x64)
        const int row = e2 >> 6, c2 = e2 & 63;
        unsigned int packed = 0;
        if (n0 + row < NN) {
            const float2 g = ((const float2*)(feat + (size_t)n0 * FD))[e2];
            packed = (unsigned int)f2bf(g.x) | ((unsigned int)f2bf(g.y) << 16);
        }
        smu[row * (LDS_STRIDE / 2) + c2] = packed;
    }
    const unsigned int* wtu = (const unsigned int*)wt;
    #pragma unroll
    for (int it = 0; it < 36; ++it) {
        const int u = t + it * 256;            // < 9216
        const int row = u >> 6, c2 = u & 63;
        smu[WT_U / 2 + row * (LDS_STRIDE / 2) + c2] = wtu[u];
    }
    __syncthreads();

    const int w = t >> 6;          // wave id = M-tile
    const int lane = t & 63;
    const int mr = lane & 15, quad = lane >> 4;

    f32x4 acc[9];
    #pragma unroll
    for (int i = 0; i < 9; ++i) acc[i] = (f32x4){0.f, 0.f, 0.f, 0.f};

    #pragma unroll
    for (int kk = 0; kk < 4; ++kk) {
        const bf16x8 a =
            *(const bf16x8*)&sm[(w * 16 + mr) * LDS_STRIDE + kk * 32 + quad * 8];
        #pragma unroll
        for (int tt = 0; tt < 9; ++tt) {
            const bf16x8 b = *(const bf16x8*)&sm[WT_U + (tt * 16 + mr) * LDS_STRIDE +
                                                 kk * 32 + quad * 8];
            acc[tt] = __builtin_amdgcn_mfma_f32_16x16x32_bf16(a, b, acc[tt], 0, 0, 0);
        }
    }

    #pragma unroll
    for (int tt = 0; tt < 8; ++tt) {
        const int col = tt * 16 + mr;
        #pragma unroll
        for (int r = 0; r < 4; ++r) {
            const int node = n0 + w * 16 + quad * 4 + r;
            if (node < NN) hc_bf[(size_t)node * FD + col] = f2bf(acc[tt][r]);
        }
    }
    #pragma unroll
    for (int r = 0; r < 4; ++r) {
        const int node = n0 + w * 16 + quad * 4 + r;
        if (node < NN) {
            if (mr < 4)      A[(size_t)node * NH + mr] = acc[8][r];
            else if (mr < 8) B[(size_t)node * NH + (mr - 4)] = acc[8][r];
        }
    }
}

// ---------------- K3: scan (3 stages) ----------------
__global__ __launch_bounds__(256) void scan1_kernel(const int* __restrict__ deg,
                                                    int* __restrict__ tmp,
                                                    int* __restrict__ bsum) {
    __shared__ int sh[256];
    const int t = threadIdx.x, b = blockIdx.x, i = b * 256 + t;
    const int v = (i < NN) ? deg[i] : 0;
    sh[t] = v;
    __syncthreads();
    #pragma unroll
    for (int off = 1; off < 256; off <<= 1) {
        const int x = (t >= off) ? sh[t - off] : 0;
        __syncthreads();
        sh[t] += x;
        __syncthreads();
    }
    if (i < NN) tmp[i] = sh[t] - v;   // exclusive
    if (t == 255) bsum[b] = sh[t];
}

__global__ __launch_bounds__(512) void scan2_kernel(int* __restrict__ bsum) {
    __shared__ int sh[512];
    const int t = threadIdx.x;
    const int v = (t < NB_SCAN) ? bsum[t] : 0;
    sh[t] = v;
    __syncthreads();
    #pragma unroll
    for (int off = 1; off < 512; off <<= 1) {
        const int x = (t >= off) ? sh[t - off] : 0;
        __syncthreads();
        sh[t] += x;
        __syncthreads();
    }
    if (t < NB_SCAN) bsum[t] = sh[t] - v;   // exclusive
}

__global__ __launch_bounds__(256) void scan3_kernel(const int* __restrict__ tmp,
                                                    const int* __restrict__ bsum,
                                                    int* __restrict__ row_ptr,
                                                    int* __restrict__ cursor) {
    const int i = blockIdx.x * 256 + threadIdx.x;
    if (i < NN) {
        const int v = tmp[i] + bsum[blockIdx.x];
        row_ptr[i] = v;
        cursor[i] = v;
    }
    if (i == 0) row_ptr[NN] = NE;
}

// ---------------- K4: scatter edges into CSR (XCD-sharded, int4) ----------
__global__ __launch_bounds__(256) void scatter_kernel(
    const int* __restrict__ src, const int* __restrict__ dst,
    int* __restrict__ cursor, int* __restrict__ col)
{
    const int shard = blockIdx.x & (NSHARD - 1);
    const int i4 = (blockIdx.x >> 3) * 256 + threadIdx.x;
    if (i4 >= NE4) return;
    const int4 d4 = ((const int4*)dst)[i4];
    const int4 s4 = ((const int4*)src)[i4];
    const int lo = shard * SHARD, hi = lo + SHARD;
    if (d4.x >= lo && d4.x < hi) col[atomicAdd(&cursor[d4.x], 1)] = s4.x;
    if (d4.y >= lo && d4.y < hi) col[atomicAdd(&cursor[d4.y], 1)] = s4.y;
    if (d4.z >= lo && d4.z < hi) col[atomicAdd(&cursor[d4.z], 1)] = s4.z;
    if (d4.w >= lo && d4.w < hi) col[atomicAdd(&cursor[d4.w], 1)] = s4.w;
}

// ---------------- K5: per-node fused softmax + aggregate ----------------
// One 64-lane wave per node, split into two 32-lane halves.
// Lane l: half = l>>5, il = l&31; owns channels [4*il, 4*il+4) (uint2 of hc
// row), head hme = il>>3. Halves process disjoint edges (4 each per 8-step).
// Exp dedup: within a half, lane j = il&7 computes w for edge j; broadcast
// via __shfl. Cross-half combine at the end with __shfl_xor(32).
__global__ __launch_bounds__(256) void agg_kernel(
    const int* __restrict__ row_ptr, const int* __restrict__ col,
    const float* __restrict__ A, const float* __restrict__ B,
    const uint2* __restrict__ hc_u2,
    const float* __restrict__ feat, float* __restrict__ out)
{
    const int n = blockIdx.x * 4 + (threadIdx.x >> 6);
    const int l = threadIdx.x & 63;
    const int half = l >> 5, il = l & 31;
    const int hme = il >> 3;
    const int gbase = l & 0x38;        // half-bit | head-group base for shfl
    const int r0 = row_ptr[n], r1 = row_ptr[n + 1];
    const float bh = B[(size_t)n * NH + hme];

    float ssum = 0.f;
    float acc0 = 0.f, acc1 = 0.f, acc2 = 0.f, acc3 = 0.f;

    int p = r0;
    // 8-edge step: half 0 -> edges 0..3, half 1 -> edges 4..7
    for (; p + 8 <= r1; p += 8) {
        int c[4];
        #pragma unroll
        for (int m = 0; m < 4; ++m) c[m] = col[p + half * 4 + m];
        uint2 u[4];
        #pragma unroll
        for (int m = 0; m < 4; ++m) u[m] = hc_u2[(size_t)c[m] * 32 + il];
        // my exp edge: j = il & 7 (covers all 8 edges per half, head = hme)
        const int ck = col[p + (il & 7)];
        float e = A[(size_t)ck * NH + hme] + bh;
        e = e > 0.f ? e : 0.2f * e;
        const float w = __expf(e);
        #pragma unroll
        for (int m = 0; m < 4; ++m) {
            const float wm = __shfl(w, gbase | (half * 4 + m));
            ssum += wm;
            acc0 = fmaf(wm, bf_lo(u[m].x), acc0);
            acc1 = fmaf(wm, bf_hi(u[m].x), acc1);
            acc2 = fmaf(wm, bf_lo(u[m].y), acc2);
            acc3 = fmaf(wm, bf_hi(u[m].y), acc3);
        }
    }
    // 4-edge step: half 0 -> edges 0,1; half 1 -> edges 2,3
    if (p + 4 <= r1) {
        int c[2];
        #pragma unroll
        for (int m = 0; m < 2; ++m) c[m] = col[p + half * 2 + m];
        uint2 u[2];
        #pragma unroll
        for (int m = 0; m < 2; ++m) u[m] = hc_u2[(size_t)c[m] * 32 + il];
        const int ck = col[p + (il & 3)];
        float e = A[(size_t)ck * NH + hme] + bh;
        e = e > 0.f ? e : 0.2f * e;
        const float w = __expf(e);
        #pragma unroll
        for (int m = 0; m < 2; ++m) {
            const float wm = __shfl(w, gbase | (half * 2 + m));
            ssum += wm;
            acc0 = fmaf(wm, bf_lo(u[m].x), acc0);
            acc1 = fmaf(wm, bf_hi(u[m].x), acc1);
            acc2 = fmaf(wm, bf_lo(u[m].y), acc2);
            acc3 = fmaf(wm, bf_hi(u[m].y), acc3);
        }
        p += 4;
    }
    // tail (<4 edges): half 0 only, per-lane exp (redundant but short)
    if (half == 0) {
        for (; p < r1; ++p) {
            const int c = col[p];
            const uint2 u = hc_u2[(size_t)c * 32 + il];
            float e = A[(size_t)c * NH + hme] + bh;
            e = e > 0.f ? e : 0.2f * e;
            const float w = __expf(e);
            ssum += w;
            acc0 = fmaf(w, bf_lo(u.x), acc0);
            acc1 = fmaf(w, bf_hi(u.x), acc1);
            acc2 = fmaf(w, bf_lo(u.y), acc2);
            acc3 = fmaf(w, bf_hi(u.y), acc3);
        }
    }

    // cross-half combine
    ssum += __shfl_xor(ssum, 32);
    acc0 += __shfl_xor(acc0, 32);
    acc1 += __shfl_xor(acc1, 32);
    acc2 += __shfl_xor(acc2, 32);
    acc3 += __shfl_xor(acc3, 32);

    if (half == 0) {
        const float inv = ssum > 0.f ? 1.f / ssum : 0.f;
        const float4 fv = ((const float4*)(feat + (size_t)n * FD))[il];
        float4 ov;
        ov.x = acc0 * inv + fv.x;
        ov.y = acc1 * inv + fv.y;
        ov.z = acc2 * inv + fv.z;
        ov.w = acc3 * inv + fv.w;
        ((float4*)(out + (size_t)n * FD))[il] = ov;
    }
    if (blockIdx.x == 0 && threadIdx.x == 0) out[(size_t)NN * FD] = 0.f;
}

// ---------------- launcher ----------------
extern "C" void kernel_launch(void* const* d_in, const int* in_sizes, int n_in,
                              void* d_out, int out_size, void* d_ws, size_t ws_size,
                              hipStream_t stream) {
    const float* feat         = (const float*)d_in[0];
    const int*   src          = (const int*)d_in[1];
    const int*   dst          = (const int*)d_in[2];
    const float* Wc           = (const float*)d_in[3];
    const float* Wp           = (const float*)d_in[4];
    const float* attn_src     = (const float*)d_in[5];
    const float* attn_dst     = (const float*)d_in[6];
    const float* pos_attn_src = (const float*)d_in[7];
    const float* pos_attn_dst = (const float*)d_in[8];
    const float* att_comb     = (const float*)d_in[9];
    float* out = (float*)d_out;

    // workspace layout (all 16B-aligned)
    char* w = (char*)d_ws;
    unsigned short* hc_bf = (unsigned short*)w;        w += (size_t)NN * FD * 2;  // 25.6 MB
    float* A       = (float*)w;                        w += (size_t)NN * NH * 4;  // 1.6 MB
    float* B       = (float*)w;                        w += (size_t)NN * NH * 4;  // 1.6 MB
    int*   deg     = (int*)w;                          w += (size_t)NN * 4;
    int*   tmp     = (int*)w;                          w += (size_t)NN * 4;
    int*   row_ptr = (int*)w;                          w += (size_t)(NN + 4) * 4;
    int*   cursor  = (int*)w;                          w += (size_t)NN * 4;
    int*   bsum    = (int*)w;                          w += 512 * 4;
    unsigned short* wt = (unsigned short*)w;           w += (size_t)NOUT * FD * 2;
    int*   col     = (int*)w;                          /* NE*4 = 6.4 MB */

    hipMemsetAsync(deg, 0, (size_t)NN * sizeof(int), stream);
    prep_kernel<<<1, 256, 0, stream>>>(Wc, Wp, attn_src, attn_dst,
                                       pos_attn_src, pos_attn_dst, att_comb, wt);
    hist_kernel<<<NSHARD * NB_E4, 256, 0, stream>>>(dst, deg);
    node_mfma_kernel<<<NGB, 256, 0, stream>>>(feat, wt, hc_bf, A, B);
    scan1_kernel<<<NB_SCAN, 256, 0, stream>>>(deg, tmp, bsum);
    scan2_kernel<<<1, 512, 0, stream>>>(bsum);
    scan3_kernel<<<NB_SCAN, 256, 0, stream>>>(tmp, bsum, row_ptr, cursor);
    scatter_kernel<<<NSHARD * NB_E4, 256, 0, stream>>>(src, dst, cursor, col);
    agg_kernel<<<NN / 4, 256, 0, stream>>>(row_ptr, col, A, B,
                                           (const uint2*)hc_bf, feat, out);
}